// Round 1
// baseline (680.675 us; speedup 1.0000x reference)
//
#include <hip/hip_runtime.h>

#define NF 8
#define NNS 4
#define NSL 7          // perm-partner slots per field
#define DIM_NS 100000
#define DIM_SEQ 1000
#define SEQ_LEN 50
#define DD 64
#define BB 16384

typedef unsigned int u32;

__device__ __forceinline__ unsigned short f2bf(float x) {
  u32 u = __float_as_uint(x);
  u32 r = (u + 0x7FFFu + ((u >> 16) & 1u)) >> 16;  // RNE
  return (unsigned short)r;
}

// packed layout: for (f, v): 64 d-entries, each 8 bf16 = slots 0..6 + zero pad.
// byte offset of (f,v,d) = ((f*1000+v)*64 + d) * 16  -> one dwordx4 per lane (lane=d)
__global__ __launch_bounds__(256) void pack_seq_kernel(const float* __restrict__ tseq,
                                                       u32* __restrict__ packed) {
  int fv = blockIdx.x * 4 + (threadIdx.x >> 6);   // 0..3999
  int d  = threadIdx.x & 63;
  int f = fv / DIM_SEQ, v = fv - f * DIM_SEQ;
  unsigned short h[8];
#pragma unroll
  for (int s = 0; s < NSL; ++s) {
    h[s] = f2bf(tseq[((size_t)((f * NSL + s) * DIM_SEQ + v)) * DD + d]);
  }
  h[7] = 0;
  uint4 val;
  val.x = (u32)h[0] | ((u32)h[1] << 16);
  val.y = (u32)h[2] | ((u32)h[3] << 16);
  val.z = (u32)h[4] | ((u32)h[5] << 16);
  val.w = (u32)h[6] | ((u32)h[7] << 16);
  *reinterpret_cast<uint4*>(packed + ((size_t)fv * DD + d) * 4) = val;
}

template <bool PACKED>
__global__ __launch_bounds__(256) void ffm_kernel(const float* __restrict__ tns,
                                                  const float* __restrict__ tseq,
                                                  const u32* __restrict__ packed,
                                                  const int* __restrict__ idx_ns,
                                                  const int* __restrict__ idx_seq,
                                                  float* __restrict__ out) {
  const int lane = threadIdx.x & 63;
  int b = (int)((blockIdx.x * blockDim.x + threadIdx.x) >> 6);  // one wave per batch elem
  b = __builtin_amdgcn_readfirstlane(b);                        // wave-uniform -> SGPR
  const int d = lane;                                           // lane owns dim d

  // ---- non-sequence embeddings: ens[field][slot] (random HBM rows, fp32) ----
  float ens[NNS][NSL];
#pragma unroll
  for (int a = 0; a < NNS; ++a) {
    const int ia = idx_ns[a * BB + b];  // scalar load (b uniform)
#pragma unroll
    for (int s = 0; s < NSL; ++s) {
      ens[a][s] = tns[((size_t)(a * NSL + s) * DIM_NS + ia) * DD + d];
    }
  }

  // ---- sequence pooled embeddings: acc[field][slot] ----
  float acc[NNS][NSL];
#pragma unroll
  for (int f = 0; f < NNS; ++f)
#pragma unroll
    for (int s = 0; s < NSL; ++s) acc[f][s] = 0.f;

#pragma unroll
  for (int f = 0; f < NNS; ++f) {
    int myidx = 0;
    if (lane < SEQ_LEN) myidx = idx_seq[(f * BB + b) * SEQ_LEN + lane];
#pragma unroll
    for (int l = 0; l < SEQ_LEN; ++l) {
      const int iv = __builtin_amdgcn_readlane(myidx, l);  // SGPR index
      if (PACKED) {
        const uint4 u = *reinterpret_cast<const uint4*>(
            packed + ((size_t)(f * DIM_SEQ + iv) * DD + d) * 4);
        acc[f][0] += __uint_as_float(u.x << 16);
        acc[f][1] += __uint_as_float(u.x & 0xFFFF0000u);
        acc[f][2] += __uint_as_float(u.y << 16);
        acc[f][3] += __uint_as_float(u.y & 0xFFFF0000u);
        acc[f][4] += __uint_as_float(u.z << 16);
        acc[f][5] += __uint_as_float(u.z & 0xFFFF0000u);
        acc[f][6] += __uint_as_float(u.w << 16);  // slot 7 is zero pad, skipped
      } else {
#pragma unroll
        for (int s = 0; s < NSL; ++s) {
          acc[f][s] += tseq[((size_t)(f * NSL + s) * DIM_SEQ + iv) * DD + d];
        }
      }
    }
  }

#pragma unroll
  for (int f = 0; f < NNS; ++f)
#pragma unroll
    for (int s = 0; s < NSL; ++s) acc[f][s] *= (1.0f / 50.0f);

  // ---- pair dots: slot of partner c in field a's table list = (c<a ? c : c-1) ----
  float r = 0.f;
#pragma unroll
  for (int a = 0; a < NF; ++a) {
#pragma unroll
    for (int c = a + 1; c < NF; ++c) {
      const float ea = (a < NNS) ? ens[a][c - 1] : acc[a - NNS][c - 1];
      const float ec = (c < NNS) ? ens[c][a] : acc[c - NNS][a];
      r += ea * ec;
    }
  }

  // ---- wave reduction over the 64 dims ----
#pragma unroll
  for (int off = 32; off > 0; off >>= 1) r += __shfl_down(r, off);
  if (lane == 0) out[b] = r;
}

extern "C" void kernel_launch(void* const* d_in, const int* in_sizes, int n_in,
                              void* d_out, int out_size, void* d_ws, size_t ws_size,
                              hipStream_t stream) {
  const float* tns    = (const float*)d_in[0];
  const float* tseq   = (const float*)d_in[1];
  const int*   idx_ns = (const int*)d_in[2];
  const int*   idx_sq = (const int*)d_in[3];
  float* out = (float*)d_out;

  const size_t packed_bytes = (size_t)NNS * DIM_SEQ * DD * 8 * 2;  // 4,096,000 B
  if (ws_size >= packed_bytes) {
    pack_seq_kernel<<<NNS * DIM_SEQ / 4, 256, 0, stream>>>(tseq, (u32*)d_ws);
    ffm_kernel<true><<<BB / 4, 256, 0, stream>>>(tns, tseq, (const u32*)d_ws,
                                                 idx_ns, idx_sq, out);
  } else {
    ffm_kernel<false><<<BB / 4, 256, 0, stream>>>(tns, tseq, nullptr,
                                                  idx_ns, idx_sq, out);
  }
}

// Round 2
// 147.146 us; speedup vs baseline: 4.6259x; 4.6259x over previous
//
#include <hip/hip_runtime.h>

#define NF 8
#define NNS 4
#define NSL 7          // perm-partner slots per field
#define DIM_NS 100000
#define DIM_SEQ 1000
#define SEQ_LEN 50
#define DD 64
#define BB 16384

typedef unsigned int u32;

__device__ __forceinline__ unsigned short f2bf(float x) {
  u32 u = __float_as_uint(x);
  u32 r = (u + 0x7FFFu + ((u >> 16) & 1u)) >> 16;  // RNE
  return (unsigned short)r;
}

// packed layout: for (f, v): 64 d-entries, each 8 bf16 = slots 0..6 + zero pad.
// byte offset of (f,v,d) = ((f*1000+v)*64 + d) * 16  -> one dwordx4 per lane (lane=d)
__global__ __launch_bounds__(256) void pack_seq_kernel(const float* __restrict__ tseq,
                                                       u32* __restrict__ packed) {
  int fv = blockIdx.x * 4 + (threadIdx.x >> 6);   // 0..3999
  int d  = threadIdx.x & 63;
  int f = fv / DIM_SEQ, v = fv - f * DIM_SEQ;
  unsigned short h[8];
#pragma unroll
  for (int s = 0; s < NSL; ++s) {
    h[s] = f2bf(tseq[((size_t)((f * NSL + s) * DIM_SEQ + v)) * DD + d]);
  }
  h[7] = 0;
  uint4 val;
  val.x = (u32)h[0] | ((u32)h[1] << 16);
  val.y = (u32)h[2] | ((u32)h[3] << 16);
  val.z = (u32)h[4] | ((u32)h[5] << 16);
  val.w = (u32)h[6] | ((u32)h[7] << 16);
  *reinterpret_cast<uint4*>(packed + ((size_t)fv * DD + d) * 4) = val;
}

// pair list: combinations(8, 2) in reference order
__device__ __constant__ int PAIR_A[28] = {0,0,0,0,0,0,0, 1,1,1,1,1,1, 2,2,2,2,2, 3,3,3,3, 4,4,4, 5,5, 6};
__device__ __constant__ int PAIR_C[28] = {1,2,3,4,5,6,7, 2,3,4,5,6,7, 3,4,5,6,7, 4,5,6,7, 5,6,7, 6,7, 7};

// One block per batch element. Wave w (0..3) owns NS field w and seq field 4+w.
// Each wave stages its 14 embedding vectors (7 NS + 7 seq-pooled) in LDS, then
// computes 7 of the 28 pair dot products from LDS.
template <bool PACKED>
__global__ __launch_bounds__(256, 4) void ffm_kernel(const float* __restrict__ tns,
                                                     const float* __restrict__ tseq,
                                                     const u32* __restrict__ packed,
                                                     const int* __restrict__ idx_ns,
                                                     const int* __restrict__ idx_seq,
                                                     float* __restrict__ out) {
  __shared__ float e_lds[NF * NSL * DD];  // 14336 B: [field][slot][d]
  __shared__ float partial[4];

  const int lane = threadIdx.x & 63;
  const int w    = threadIdx.x >> 6;  // wave id 0..3
  const int b    = blockIdx.x;
  const int d    = lane;

  // ---- NS field w: 7 random rows from HBM, fp32, coalesced 256B each ----
  {
    const int ia = idx_ns[w * BB + b];  // wave-uniform scalar load
#pragma unroll
    for (int s = 0; s < NSL; ++s) {
      e_lds[(w * NSL + s) * DD + d] =
          tns[((size_t)(w * NSL + s) * DIM_NS + ia) * DD + d];
    }
  }

  // ---- seq field 4+w: mean-pool 50 gathered rows ----
  {
    float acc[NSL];
#pragma unroll
    for (int s = 0; s < NSL; ++s) acc[s] = 0.f;

    int myidx = 0;
    if (lane < SEQ_LEN) myidx = idx_seq[(w * BB + b) * SEQ_LEN + lane];

    if (PACKED) {
#pragma unroll 10
      for (int l = 0; l < SEQ_LEN; ++l) {
        const int iv = __builtin_amdgcn_readlane(myidx, l);  // SGPR index
        const uint4 u = *reinterpret_cast<const uint4*>(
            packed + ((size_t)(w * DIM_SEQ + iv) * DD + d) * 4);
        acc[0] += __uint_as_float(u.x << 16);
        acc[1] += __uint_as_float(u.x & 0xFFFF0000u);
        acc[2] += __uint_as_float(u.y << 16);
        acc[3] += __uint_as_float(u.y & 0xFFFF0000u);
        acc[4] += __uint_as_float(u.z << 16);
        acc[5] += __uint_as_float(u.z & 0xFFFF0000u);
        acc[6] += __uint_as_float(u.w << 16);  // slot 7 is zero pad
      }
    } else {
#pragma unroll 5
      for (int l = 0; l < SEQ_LEN; ++l) {
        const int iv = __builtin_amdgcn_readlane(myidx, l);
#pragma unroll
        for (int s = 0; s < NSL; ++s) {
          acc[s] += tseq[((size_t)(w * NSL + s) * DIM_SEQ + iv) * DD + d];
        }
      }
    }

#pragma unroll
    for (int s = 0; s < NSL; ++s) {
      e_lds[((NNS + w) * NSL + s) * DD + d] = acc[s] * (1.0f / 50.0f);
    }
  }

  __syncthreads();

  // ---- 7 pair dots per wave from LDS ----
  // pair (a,c), a<c: a's slot for c is (c-1); c's slot for a is a.
  float r = 0.f;
#pragma unroll
  for (int p = 0; p < NSL; ++p) {
    const int pi = w * NSL + p;      // wave-uniform
    const int a  = PAIR_A[pi];
    const int c  = PAIR_C[pi];
    r += e_lds[(a * NSL + (c - 1)) * DD + d] * e_lds[(c * NSL + a) * DD + d];
  }

  // ---- reduce 64 lanes, then 4 waves ----
#pragma unroll
  for (int off = 32; off > 0; off >>= 1) r += __shfl_down(r, off);
  if (lane == 0) partial[w] = r;
  __syncthreads();
  if (threadIdx.x == 0) out[b] = partial[0] + partial[1] + partial[2] + partial[3];
}

extern "C" void kernel_launch(void* const* d_in, const int* in_sizes, int n_in,
                              void* d_out, int out_size, void* d_ws, size_t ws_size,
                              hipStream_t stream) {
  const float* tns    = (const float*)d_in[0];
  const float* tseq   = (const float*)d_in[1];
  const int*   idx_ns = (const int*)d_in[2];
  const int*   idx_sq = (const int*)d_in[3];
  float* out = (float*)d_out;

  const size_t packed_bytes = (size_t)NNS * DIM_SEQ * DD * 8 * 2;  // 4,096,000 B
  if (ws_size >= packed_bytes) {
    pack_seq_kernel<<<NNS * DIM_SEQ / 4, 256, 0, stream>>>(tseq, (u32*)d_ws);
    ffm_kernel<true><<<BB, 256, 0, stream>>>(tns, tseq, (const u32*)d_ws,
                                             idx_ns, idx_sq, out);
  } else {
    ffm_kernel<false><<<BB, 256, 0, stream>>>(tns, tseq, nullptr,
                                              idx_ns, idx_sq, out);
  }
}